// Round 12
// baseline (448.311 us; speedup 1.0000x reference)
//
#include <hip/hip_runtime.h>
#include <math.h>

#define VOCAB 32000
#define DIM 1024
#define SS 512
#define BS 1024
#define MASK_ID 31999
#define EXPAND_ID 31998
#define NSTEPS 4
#define TOPK 50
#define PW 4               // max new rows per pass
#define ROWS 16            // total row-cache slots
#define NDCL 16            // logits K-chunks (64 d each)
#define NCH 500            // 64-col chunks per row
#define THRRANK 49         // T = 50th-largest chunk max -> >=50 values >= T
#define CAP 768
#define COMB_BLOCKS 500    // 125 x 4
#define NEGF (-3.4028234663852886e38f)

// -------- persistent device state (re-initialized every kernel_launch) ------
__device__ int   g_x[BS];
__device__ int   g_tok[ROWS];      // cached-row tokens (CAS/dedup appended)
__device__ int   g_ntok;           // total tokens (incl. not-yet-computed)
__device__ int   g_pbase;          // base slot of current pass
__device__ int   g_pn;             // row count of current pass
__device__ float g_h[PW][DIM];
__device__ float g_lpart[NDCL][PW][VOCAB];
__device__ float g_rows[ROWS][VOCAB];
__device__ float g_cmax[ROWS][NCH];
__device__ int   g_camax[ROWS][NCH];
__device__ float g_cz[ROWS][NCH];
__device__ int   g_rowx0[ROWS];    // per-row first-index argmax (= token id)
__device__ float g_rowconf[ROWS];
__device__ int   g_done;           // comb tail counter
__device__ int   g_done2;          // conf tail counter

__device__ inline unsigned keyf(float f) {
    unsigned b = __float_as_uint(f);
    return b ^ ((b & 0x80000000u) ? 0xFFFFFFFFu : 0x80000000u);
}

// 1 block, 1024 threads: init + pass-1 token set (CAS dedup)
__global__ __launch_bounds__(1024) void k_start(const int* __restrict__ x) {
    int p = threadIdx.x;
    g_x[p] = x[p];
    if (p < ROWS) g_tok[p] = -1;
    if (p == 0) { g_done = 0; g_done2 = 0; }
    __syncthreads();
    if (g_x[p] == MASK_ID) {
        int s = p & (SS - 1);
        int t = g_x[(s == 0) ? p : p - 1];
        for (int r = 0; r < PW; r++) {
            int old = atomicCAS(&g_tok[r], -1, t);
            if (old == -1 || old == t) break;
        }
    }
    __syncthreads();
    if (p == 0) {
        int n = 0;
        while (n < PW && g_tok[n] >= 0) n++;
        g_pbase = 0; g_pn = n; g_ntok = n;
    }
}

// h = tanh(emb[tok] @ W1), full-K: grid 32, block 1024 = 32 cols x 32 K-groups
__global__ __launch_bounds__(1024) void k_h(const float* __restrict__ emb,
                                            const float* __restrict__ W1) {
    __shared__ int   s_pn, s_pb;
    __shared__ float se[PW][DIM];      // 16 KB
    __shared__ float red[32][33];      // padded
    int tid = threadIdx.x, bid = blockIdx.x;
    if (tid == 0) { s_pn = g_pn; s_pb = g_pbase; }
    __syncthreads();
    const int pn = s_pn;
    if (pn == 0) return;
    for (int i = tid; i < pn * DIM; i += 1024) {
        int j = i >> 10, d = i & (DIM - 1);
        se[j][d] = emb[(size_t)g_tok[s_pb + j] * DIM + d];
    }
    __syncthreads();
    const int ct = tid & 31, kg = tid >> 5;
    const int col = bid * 32 + ct;
    float acc[PW] = {0.f, 0.f, 0.f, 0.f};
    #pragma unroll 4
    for (int dd = 0; dd < 32; dd++) {
        int d = kg * 32 + dd;
        float w = W1[(size_t)d * DIM + col];
        #pragma unroll
        for (int j = 0; j < PW; j++)
            if (j < pn) acc[j] += se[j][d] * w;
    }
    for (int j = 0; j < pn; j++) {             // pn is block-uniform
        red[kg][ct] = acc[j];
        __syncthreads();
        for (int o = 16; o; o >>= 1) {
            if (kg < o) red[kg][ct] += red[kg + o][ct];
            __syncthreads();
        }
        if (kg == 0) g_h[j][col] = tanhf(red[0][ct]);
        __syncthreads();
    }
}

// row-count-specialized split-K accumulate (static register indices)
template<int NA>
__device__ __forceinline__ void accumL(const float* __restrict__ Wout,
                                       const float (*sh)[64], int dc, int c) {
    float4 acc[NA];
    #pragma unroll
    for (int r = 0; r < NA; r++) acc[r] = make_float4(0.f, 0.f, 0.f, 0.f);
    const float* W = Wout + (size_t)dc * 64 * VOCAB + c;
    #pragma unroll 4
    for (int dd = 0; dd < 64; dd++) {
        float4 w = *(const float4*)(W + (size_t)dd * VOCAB);
        #pragma unroll
        for (int r = 0; r < NA; r++) {
            float s = sh[r][dd];
            acc[r].x += s * w.x; acc[r].y += s * w.y;
            acc[r].z += s * w.z; acc[r].w += s * w.w;
        }
    }
    #pragma unroll
    for (int r = 0; r < NA; r++)
        *(float4*)&g_lpart[dc][r][c] = acc[r];
}

// logits split-K partials: grid (63, NDCL), block 128 (4 cols/thread)
__global__ __launch_bounds__(128) void k_logits(const float* __restrict__ Wout) {
    __shared__ float sh[PW][64];
    __shared__ int s_pn;
    int tid = threadIdx.x, dc = blockIdx.y;
    if (tid == 0) s_pn = g_pn;
    __syncthreads();
    const int pn = s_pn;
    if (pn == 0) return;
    for (int i = tid; i < PW * 64; i += 128) {
        int j = i >> 6, dd = i & 63;
        sh[j][dd] = (j < pn) ? g_h[j][dc * 64 + dd] : 0.f;
    }
    __syncthreads();
    int c = blockIdx.x * 512 + tid * 4;
    if (c >= VOCAB) return;
    switch (pn) {
        case 1: accumL<1>(Wout, sh, dc, c); break;
        case 2: accumL<2>(Wout, sh, dc, c); break;
        case 3: accumL<3>(Wout, sh, dc, c); break;
        default: accumL<PW>(Wout, sh, dc, c); break;
    }
}

// combine + penalty + per-64-chunk wave stats; LAST block does the tiny
// "next tokens" phase (row argmax + dedup append). grid (125, PW), block 256.
__global__ __launch_bounds__(256) void k_comb_stats() {
    __shared__ int s_tail;
    __shared__ float rf[256];
    __shared__ int   ri[256];
    int tid = threadIdx.x;
    int j = blockIdx.y;
    const int pn = g_pn, base = g_pbase;
    if (j < pn) {
        int slot = base + j;
        int wv = tid >> 6, lane = tid & 63;
        int chunk = blockIdx.x * 4 + wv;             // < 500
        int c = chunk * 64 + lane;
        float v = 0.f;
        #pragma unroll
        for (int dc = 0; dc < NDCL; dc++) v += g_lpart[dc][j][c];
        if (c == EXPAND_ID) v -= 1e9f;
        g_rows[slot][c] = v;
        float bv = v; int bi = c;
        #pragma unroll
        for (int off = 1; off < 64; off <<= 1) {
            float ov = __shfl_xor(bv, off, 64);
            int   oi = __shfl_xor(bi, off, 64);
            if (ov > bv || (ov == bv && oi < bi)) { bv = ov; bi = oi; }
        }
        float z = expf(v - bv);
        #pragma unroll
        for (int off = 1; off < 64; off <<= 1)
            z += __shfl_xor(z, off, 64);
        if (lane == 0) {
            g_cmax[slot][chunk]  = bv;
            g_camax[slot][chunk] = bi;
            g_cz[slot][chunk]    = z;
        }
    }
    // ---- done-counter: last of 500 blocks runs the "next" phase ----
    __threadfence();
    if (tid == 0) s_tail = (atomicAdd(&g_done, 1) == COMB_BLOCKS - 1);
    __syncthreads();
    if (!s_tail) return;
    __threadfence();
    for (int jj = 0; jj < pn; jj++) {
        int slot = base + jj;
        float bv = NEGF; int bi = 0x7fffffff;
        for (int ch = tid; ch < NCH; ch += 256) {
            float v2 = g_cmax[slot][ch]; int i2 = g_camax[slot][ch];
            if (v2 > bv || (v2 == bv && i2 < bi)) { bv = v2; bi = i2; }
        }
        rf[tid] = bv; ri[tid] = bi;
        __syncthreads();
        for (int o = 128; o; o >>= 1) {
            if (tid < o) {
                if (rf[tid + o] > rf[tid] ||
                    (rf[tid + o] == rf[tid] && ri[tid + o] < ri[tid])) {
                    rf[tid] = rf[tid + o]; ri[tid] = ri[tid + o];
                }
            }
            __syncthreads();
        }
        if (tid == 0) g_rowx0[slot] = ri[0];
        __syncthreads();
    }
    if (tid == 0) {
        int nt = g_ntok;
        int nb = nt;
        for (int jj = 0; jj < pn; jj++) {
            int t = g_rowx0[base + jj];
            bool found = false;
            for (int k = 0; k < nt; k++) if (g_tok[k] == t) { found = true; break; }
            if (!found && nt < ROWS) g_tok[nt++] = t;
        }
        g_pbase = nb; g_pn = nt - nb; g_ntok = nt;
        g_done = 0;                              // reset for next pass
    }
}

// per-row conf (parallel across rows); LAST block replays the 4 selection
// steps in LDS and writes the output. grid ROWS, block 1024.
__global__ __launch_bounds__(1024) void k_conf(float* __restrict__ out) {
    __shared__ float rf[1024];
    __shared__ float cmv[512];
    __shared__ float cand[CAP];
    __shared__ float sorted_[TOPK];
    __shared__ int s_n;
    __shared__ float s_mx, s_Z;
    __shared__ unsigned s_thr;
    __shared__ int s_tail;
    int tid = threadIdx.x;
    int slot = blockIdx.x;
    const int nrows = g_pbase;          // rows with computed data
    if (slot < nrows) {
        // row max
        rf[tid] = (tid < NCH) ? g_cmax[slot][tid] : NEGF;
        __syncthreads();
        for (int o = 512; o; o >>= 1) {
            if (tid < o) rf[tid] = fmaxf(rf[tid], rf[tid + o]);
            __syncthreads();
        }
        if (tid == 0) s_mx = rf[0];
        __syncthreads();
        float mx = s_mx;
        // Z
        rf[tid] = (tid < NCH) ? g_cz[slot][tid] * expf(g_cmax[slot][tid] - mx) : 0.f;
        __syncthreads();
        for (int o = 512; o; o >>= 1) {
            if (tid < o) rf[tid] += rf[tid + o];
            __syncthreads();
        }
        if (tid == 0) { s_Z = rf[0]; s_n = 0; }
        __syncthreads();
        // threshold: 50th-largest chunk max (rank-select over 500)
        if (tid < 512) cmv[tid] = (tid < NCH) ? g_cmax[slot][tid] : NEGF;
        __syncthreads();
        if (tid < NCH) {
            unsigned kt = keyf(cmv[tid]);
            int rank = 0;
            for (int j = 0; j < NCH; j++) {
                unsigned kj = keyf(cmv[j]);
                rank += (kj > kt) || (kj == kt && j < tid);
            }
            if (rank == THRRANK) s_thr = kt;
        }
        __syncthreads();
        unsigned T = s_thr;
        // gather candidates >= T
        const float4* L4 = (const float4*)g_rows[slot];
        for (int i = tid; i < VOCAB / 4; i += 1024) {
            float4 v4 = L4[i];
            float vv[4] = {v4.x, v4.y, v4.z, v4.w};
            #pragma unroll
            for (int q = 0; q < 4; q++) {
                if (keyf(vv[q]) >= T) {
                    int j = atomicAdd(&s_n, 1);
                    if (j < CAP) cand[j] = vv[q];
                }
            }
        }
        __syncthreads();
        int n = s_n; if (n > CAP) n = CAP;
        // rank-sort top-50 (distinct keys -> order-independent)
        for (int i = tid; i < n; i += 1024) {
            unsigned ki = keyf(cand[i]);
            int rank = 0;
            for (int j = 0; j < n; j++) {
                unsigned kj = keyf(cand[j]);
                rank += (kj > ki) || (kj == ki && j < i);
            }
            if (rank < TOPK) sorted_[rank] = cand[i];
        }
        __syncthreads();
        if (tid == 0) {
            int m = n; if (m > TOPK) m = TOPK;
            float run = expf(sorted_[0] - s_mx);     // == 1
            float lim = 0.9f * s_Z;
            for (int j = 1; j < m; j++) {
                if (run > lim) break;                // top-p removal boundary
                run += expf(sorted_[j] - s_mx);
            }
            g_rowconf[slot] = 1.0f / run;
        }
    }
    // ---- done-counter: last of ROWS blocks replays selection ----
    __threadfence();
    if (tid == 0) s_tail = (atomicAdd(&g_done2, 1) == ROWS - 1);
    __syncthreads();
    if (!s_tail) return;
    __threadfence();
    {
        __shared__ int   xl[BS];
        __shared__ int   ri2[1024];
        __shared__ int   px0[BS];
        __shared__ int   rtok[ROWS];
        __shared__ float rcf[ROWS];
        __shared__ int   rx0[ROWS];
        __shared__ float stepc[NSTEPS];
        int p = tid;
        xl[p] = g_x[p];
        if (p < ROWS) { rtok[p] = g_tok[p]; rcf[p] = g_rowconf[p]; rx0[p] = g_rowx0[p]; }
        __syncthreads();
        const int nt = nrows;
        for (int step = 0; step < NSTEPS; step++) {
            float mc = NEGF; int mx0 = 0;
            if (xl[p] == MASK_ID) {
                int s = p & (SS - 1);
                int t = xl[(s == 0) ? p : p - 1];
                for (int k = 0; k < nt; k++) {
                    if (rtok[k] == t) { mc = rcf[k]; mx0 = rx0[k]; break; }
                }
            }
            px0[p] = mx0;
            rf[p] = mc; ri2[p] = p;
            __syncthreads();
            for (int o = 512; o; o >>= 1) {
                if (p < o) {
                    if (rf[p + o] > rf[p] ||
                        (rf[p + o] == rf[p] && ri2[p + o] < ri2[p])) {
                        rf[p] = rf[p + o]; ri2[p] = ri2[p + o];
                    }
                }
                __syncthreads();
            }
            if (p == 0) {
                stepc[step] = rf[0];
                if (rf[0] > 0.f) xl[ri2[0]] = px0[ri2[0]];   // any-mask guard
            }
            __syncthreads();
        }
        out[p] = (float)xl[p];
        if (p < NSTEPS) out[BS + p] = stepc[p];
    }
}

extern "C" void kernel_launch(void* const* d_in, const int* in_sizes, int n_in,
                              void* d_out, int out_size, void* d_ws, size_t ws_size,
                              hipStream_t stream) {
    const int*   x    = (const int*)  d_in[0];
    const float* emb  = (const float*)d_in[1];
    const float* W1   = (const float*)d_in[2];
    const float* Wout = (const float*)d_in[3];
    float*       out  = (float*)d_out;

    k_start<<<1, 1024, 0, stream>>>(x);
    for (int pass = 0; pass < NSTEPS; pass++) {
        k_h<<<32, 1024, 0, stream>>>(emb, W1);
        k_logits<<<dim3(63, NDCL), 128, 0, stream>>>(Wout);
        k_comb_stats<<<dim3(125, PW), 256, 0, stream>>>();
    }
    k_conf<<<ROWS, 1024, 0, stream>>>(out);
}

// Round 13
// 285.418 us; speedup vs baseline: 1.5707x; 1.5707x over previous
//
#include <hip/hip_runtime.h>
#include <math.h>

#define VOCAB 32000
#define DIM 1024
#define SS 512
#define BS 1024
#define MASK_ID 31999
#define EXPAND_ID 31998
#define NSTEPS 4
#define TOPK 50
#define PW 4               // max new rows per pass
#define ROWS 16            // total row-cache slots
#define NDCL 16            // logits K-chunks (64 d each)
#define NCH 500            // 64-col chunks per row
#define THRRANK 49         // T = 50th-largest chunk max -> >=50 values >= T
#define CAP 768
#define NEGF (-3.4028234663852886e38f)

// -------- persistent device state (re-initialized every kernel_launch) ------
__device__ int   g_x[BS];
__device__ int   g_tok[ROWS];      // cached-row tokens (CAS/dedup appended)
__device__ int   g_ntok;           // total tokens (incl. not-yet-computed)
__device__ int   g_pbase;          // base slot of current pass
__device__ int   g_pn;             // row count of current pass
__device__ float g_h[PW][DIM];
__device__ float g_lpart[NDCL][PW][VOCAB];
__device__ float g_rows[ROWS][VOCAB];
__device__ float g_cmax[ROWS][NCH];
__device__ float g_cz[ROWS][NCH];
__device__ unsigned long long g_rowkey[ROWS];  // packed (keyf(max) << 32) | (MAXI - idx)
__device__ int   g_rowx0[ROWS];    // per-row first-index argmax (= token id)
__device__ float g_rowconf[ROWS];

__device__ inline unsigned keyf(float f) {
    unsigned b = __float_as_uint(f);
    return b ^ ((b & 0x80000000u) ? 0xFFFFFFFFu : 0x80000000u);
}

// 1 block, 1024 threads: init + pass-1 token set (CAS dedup)
__global__ __launch_bounds__(1024) void k_start(const int* __restrict__ x) {
    int p = threadIdx.x;
    g_x[p] = x[p];
    if (p < ROWS) { g_tok[p] = -1; g_rowkey[p] = 0ull; }
    __syncthreads();
    if (g_x[p] == MASK_ID) {
        int s = p & (SS - 1);
        int t = g_x[(s == 0) ? p : p - 1];
        for (int r = 0; r < PW; r++) {
            int old = atomicCAS(&g_tok[r], -1, t);
            if (old == -1 || old == t) break;
        }
    }
    __syncthreads();
    if (p == 0) {
        int n = 0;
        while (n < PW && g_tok[n] >= 0) n++;
        g_pbase = 0; g_pn = n; g_ntok = n;
    }
}

// h = tanh(emb[tok] @ W1), full-K: grid 32, block 1024 = 32 cols x 32 K-groups
__global__ __launch_bounds__(1024) void k_h(const float* __restrict__ emb,
                                            const float* __restrict__ W1) {
    __shared__ int   s_pn, s_pb;
    __shared__ float se[PW][DIM];      // 16 KB
    __shared__ float red[32][33];      // padded
    int tid = threadIdx.x, bid = blockIdx.x;
    if (tid == 0) { s_pn = g_pn; s_pb = g_pbase; }
    __syncthreads();
    const int pn = s_pn;
    if (pn == 0) return;
    for (int i = tid; i < pn * DIM; i += 1024) {
        int j = i >> 10, d = i & (DIM - 1);
        se[j][d] = emb[(size_t)g_tok[s_pb + j] * DIM + d];
    }
    __syncthreads();
    const int ct = tid & 31, kg = tid >> 5;
    const int col = bid * 32 + ct;
    float acc[PW] = {0.f, 0.f, 0.f, 0.f};
    #pragma unroll 4
    for (int dd = 0; dd < 32; dd++) {
        int d = kg * 32 + dd;
        float w = W1[(size_t)d * DIM + col];
        #pragma unroll
        for (int j = 0; j < PW; j++)
            if (j < pn) acc[j] += se[j][d] * w;
    }
    for (int j = 0; j < pn; j++) {             // pn is block-uniform
        red[kg][ct] = acc[j];
        __syncthreads();
        for (int o = 16; o; o >>= 1) {
            if (kg < o) red[kg][ct] += red[kg + o][ct];
            __syncthreads();
        }
        if (kg == 0) g_h[j][col] = tanhf(red[0][ct]);
        __syncthreads();
    }
}

// row-count-specialized split-K accumulate (static register indices)
template<int NA>
__device__ __forceinline__ void accumL(const float* __restrict__ Wout,
                                       const float (*sh)[64], int dc, int c) {
    float4 acc[NA];
    #pragma unroll
    for (int r = 0; r < NA; r++) acc[r] = make_float4(0.f, 0.f, 0.f, 0.f);
    const float* W = Wout + (size_t)dc * 64 * VOCAB + c;
    #pragma unroll 4
    for (int dd = 0; dd < 64; dd++) {
        float4 w = *(const float4*)(W + (size_t)dd * VOCAB);
        #pragma unroll
        for (int r = 0; r < NA; r++) {
            float s = sh[r][dd];
            acc[r].x += s * w.x; acc[r].y += s * w.y;
            acc[r].z += s * w.z; acc[r].w += s * w.w;
        }
    }
    #pragma unroll
    for (int r = 0; r < NA; r++)
        *(float4*)&g_lpart[dc][r][c] = acc[r];
}

// logits split-K partials: grid (63, NDCL), block 128 (4 cols/thread)
__global__ __launch_bounds__(128) void k_logits(const float* __restrict__ Wout) {
    __shared__ float sh[PW][64];
    __shared__ int s_pn;
    int tid = threadIdx.x, dc = blockIdx.y;
    if (tid == 0) s_pn = g_pn;
    __syncthreads();
    const int pn = s_pn;
    if (pn == 0) return;
    for (int i = tid; i < PW * 64; i += 128) {
        int j = i >> 6, dd = i & 63;
        sh[j][dd] = (j < pn) ? g_h[j][dc * 64 + dd] : 0.f;
    }
    __syncthreads();
    int c = blockIdx.x * 512 + tid * 4;
    if (c >= VOCAB) return;
    switch (pn) {
        case 1: accumL<1>(Wout, sh, dc, c); break;
        case 2: accumL<2>(Wout, sh, dc, c); break;
        case 3: accumL<3>(Wout, sh, dc, c); break;
        default: accumL<PW>(Wout, sh, dc, c); break;
    }
}

// combine + penalty + per-64-chunk wave stats: grid (125, PW), block 256.
// Row argmax via order-independent packed atomicMax (pre-checked).
__global__ __launch_bounds__(256) void k_comb_stats() {
    int j = blockIdx.y;
    if (j >= g_pn) return;
    int slot = g_pbase + j;
    int wv = threadIdx.x >> 6, lane = threadIdx.x & 63;
    int chunk = blockIdx.x * 4 + wv;             // < 500
    int c = chunk * 64 + lane;
    float v = 0.f;
    #pragma unroll
    for (int dc = 0; dc < NDCL; dc++) v += g_lpart[dc][j][c];
    if (c == EXPAND_ID) v -= 1e9f;
    g_rows[slot][c] = v;
    float bv = v; int bi = c;
    #pragma unroll
    for (int off = 1; off < 64; off <<= 1) {
        float ov = __shfl_xor(bv, off, 64);
        int   oi = __shfl_xor(bi, off, 64);
        if (ov > bv || (ov == bv && oi < bi)) { bv = ov; bi = oi; }
    }
    float z = expf(v - bv);
    #pragma unroll
    for (int off = 1; off < 64; off <<= 1)
        z += __shfl_xor(z, off, 64);
    if (lane == 0) {
        g_cmax[slot][chunk] = bv;
        g_cz[slot][chunk]   = z;
        unsigned long long key =
            ((unsigned long long)keyf(bv) << 32) |
            (unsigned long long)(0x7fffffffu - (unsigned)bi);
        if (key > g_rowkey[slot])                // pre-check cuts atomic count
            atomicMax(&g_rowkey[slot], key);
    }
}

// tiny: extract row argmaxes from packed keys + dedup-append next tokens
__global__ __launch_bounds__(64) void k_next() {
    if (threadIdx.x != 0) return;
    int pn = g_pn, base = g_pbase;
    int nt = g_ntok;
    int nb = nt;
    for (int jj = 0; jj < pn; jj++) {
        int slot = base + jj;
        unsigned long long key = g_rowkey[slot];
        int t = (int)(0x7fffffffu - (unsigned)(key & 0xffffffffu));
        g_rowx0[slot] = t;
        bool found = false;
        for (int k = 0; k < nt; k++) if (g_tok[k] == t) { found = true; break; }
        if (!found && nt < ROWS) g_tok[nt++] = t;
    }
    g_pbase = nb; g_pn = nt - nb; g_ntok = nt;
}

// per-row conf, fully parallel across rows: grid ROWS, block 1024
__global__ __launch_bounds__(1024) void k_conf() {
    int slot = blockIdx.x;
    if (slot >= g_pbase) return;        // only rows with computed data
    __shared__ float rf[1024];
    __shared__ float cmv[512];
    __shared__ float cand[CAP];
    __shared__ float sorted_[TOPK];
    __shared__ int s_n;
    __shared__ float s_mx, s_Z;
    __shared__ unsigned s_thr;
    int tid = threadIdx.x;
    // row max
    rf[tid] = (tid < NCH) ? g_cmax[slot][tid] : NEGF;
    __syncthreads();
    for (int o = 512; o; o >>= 1) {
        if (tid < o) rf[tid] = fmaxf(rf[tid], rf[tid + o]);
        __syncthreads();
    }
    if (tid == 0) s_mx = rf[0];
    __syncthreads();
    float mx = s_mx;
    // Z
    rf[tid] = (tid < NCH) ? g_cz[slot][tid] * expf(g_cmax[slot][tid] - mx) : 0.f;
    __syncthreads();
    for (int o = 512; o; o >>= 1) {
        if (tid < o) rf[tid] += rf[tid + o];
        __syncthreads();
    }
    if (tid == 0) { s_Z = rf[0]; s_n = 0; }
    __syncthreads();
    // threshold: 50th-largest chunk max (rank-select over 500)
    if (tid < 512) cmv[tid] = (tid < NCH) ? g_cmax[slot][tid] : NEGF;
    __syncthreads();
    if (tid < NCH) {
        unsigned kt = keyf(cmv[tid]);
        int rank = 0;
        for (int j = 0; j < NCH; j++) {
            unsigned kj = keyf(cmv[j]);
            rank += (kj > kt) || (kj == kt && j < tid);
        }
        if (rank == THRRANK) s_thr = kt;
    }
    __syncthreads();
    unsigned T = s_thr;
    // gather candidates >= T
    const float4* L4 = (const float4*)g_rows[slot];
    for (int i = tid; i < VOCAB / 4; i += 1024) {
        float4 v4 = L4[i];
        float vv[4] = {v4.x, v4.y, v4.z, v4.w};
        #pragma unroll
        for (int q = 0; q < 4; q++) {
            if (keyf(vv[q]) >= T) {
                int j = atomicAdd(&s_n, 1);
                if (j < CAP) cand[j] = vv[q];
            }
        }
    }
    __syncthreads();
    int n = s_n; if (n > CAP) n = CAP;
    // rank-sort top-50 (distinct keys -> order-independent)
    for (int i = tid; i < n; i += 1024) {
        unsigned ki = keyf(cand[i]);
        int rank = 0;
        for (int j = 0; j < n; j++) {
            unsigned kj = keyf(cand[j]);
            rank += (kj > ki) || (kj == ki && j < i);
        }
        if (rank < TOPK) sorted_[rank] = cand[i];
    }
    __syncthreads();
    if (tid == 0) {
        int m = n; if (m > TOPK) m = TOPK;
        float run = expf(sorted_[0] - mx);       // == 1
        float lim = 0.9f * s_Z;
        for (int j = 1; j < m; j++) {
            if (run > lim) break;                // top-p removal boundary
            run += expf(sorted_[j] - mx);
        }
        g_rowconf[slot] = 1.0f / run;
    }
}

// 1 block, 1024 threads: replay all 4 selection steps in LDS + write output
__global__ __launch_bounds__(1024) void k_select(float* __restrict__ out) {
    __shared__ int   xl[BS];
    __shared__ float rf[1024];
    __shared__ int   ri[1024];
    __shared__ int   px0[BS];
    __shared__ int   rtok[ROWS];
    __shared__ float rcf[ROWS];
    __shared__ int   rx0[ROWS];
    __shared__ float stepc[NSTEPS];
    __shared__ int s_nt;
    int p = threadIdx.x;
    xl[p] = g_x[p];
    if (p < ROWS) { rtok[p] = g_tok[p]; rcf[p] = g_rowconf[p]; rx0[p] = g_rowx0[p]; }
    if (p == 0) s_nt = g_pbase;              // computed rows only
    __syncthreads();
    const int nt = s_nt;
    for (int step = 0; step < NSTEPS; step++) {
        float mc = NEGF; int mx0 = 0;
        if (xl[p] == MASK_ID) {
            int s = p & (SS - 1);
            int t = xl[(s == 0) ? p : p - 1];
            for (int k = 0; k < nt; k++) {
                if (rtok[k] == t) { mc = rcf[k]; mx0 = rx0[k]; break; }
            }
        }
        px0[p] = mx0;
        rf[p] = mc; ri[p] = p;
        __syncthreads();
        for (int o = 512; o; o >>= 1) {
            if (p < o) {
                if (rf[p + o] > rf[p] ||
                    (rf[p + o] == rf[p] && ri[p + o] < ri[p])) {
                    rf[p] = rf[p + o]; ri[p] = ri[p + o];
                }
            }
            __syncthreads();
        }
        if (p == 0) {
            stepc[step] = rf[0];
            if (rf[0] > 0.f) xl[ri[0]] = px0[ri[0]];   // any-mask guard
        }
        __syncthreads();
    }
    out[p] = (float)xl[p];
    if (p < NSTEPS) out[BS + p] = stepc[p];
}

extern "C" void kernel_launch(void* const* d_in, const int* in_sizes, int n_in,
                              void* d_out, int out_size, void* d_ws, size_t ws_size,
                              hipStream_t stream) {
    const int*   x    = (const int*)  d_in[0];
    const float* emb  = (const float*)d_in[1];
    const float* W1   = (const float*)d_in[2];
    const float* Wout = (const float*)d_in[3];
    float*       out  = (float*)d_out;

    k_start<<<1, 1024, 0, stream>>>(x);
    for (int pass = 0; pass < NSTEPS; pass++) {
        k_h<<<32, 1024, 0, stream>>>(emb, W1);
        k_logits<<<dim3(63, NDCL), 128, 0, stream>>>(Wout);
        k_comb_stats<<<dim3(125, PW), 256, 0, stream>>>();
        k_next<<<1, 64, 0, stream>>>();
    }
    k_conf<<<ROWS, 1024, 0, stream>>>();
    k_select<<<1, 1024, 0, stream>>>(out);
}

// Round 14
// 231.158 us; speedup vs baseline: 1.9394x; 1.2347x over previous
//
#include <hip/hip_runtime.h>
#include <math.h>

#define VOCAB 32000
#define DIM 1024
#define SS 512
#define BS 1024
#define MASK_ID 31999
#define EXPAND_ID 31998
#define NSTEPS 4
#define TOPK 50
#define PW 4               // max new rows per pass
#define ROWS 16            // total row-cache slots
#define KC 16              // h K-chunks (64 d each)
#define NDCL 16            // logits K-chunks (64 d each)
#define NCH 500            // 64-col chunks per row
#define THRRANK 49         // T = 50th-largest chunk max -> >=50 values >= T
#define CAP 768
#define NEGF (-3.4028234663852886e38f)

// -------- persistent device state (re-initialized every kernel_launch) ------
__device__ int   g_x[BS];
__device__ int   g_tok[ROWS];      // cached-row tokens (CAS/dedup appended)
__device__ int   g_ntok;           // total tokens (incl. not-yet-computed)
__device__ int   g_pbase;          // base slot of current pass
__device__ int   g_pn;             // row count of current pass
__device__ float g_hp[KC][PW][DIM];
__device__ float g_lpart[NDCL][PW][VOCAB];
__device__ float g_rows[ROWS][VOCAB];
__device__ float g_cmax[ROWS][NCH];
__device__ int   g_camax[ROWS][NCH];
__device__ float g_cz[ROWS][NCH];
__device__ int   g_rowx0[ROWS];    // per-row first-index argmax (= token id)
__device__ float g_rowconf[ROWS];

__device__ inline unsigned keyf(float f) {
    unsigned b = __float_as_uint(f);
    return b ^ ((b & 0x80000000u) ? 0xFFFFFFFFu : 0x80000000u);
}

// 1 block, 1024 threads: init + pass-1 token set (CAS dedup)
__global__ __launch_bounds__(1024) void k_start(const int* __restrict__ x) {
    int p = threadIdx.x;
    g_x[p] = x[p];
    if (p < ROWS) g_tok[p] = -1;
    __syncthreads();
    if (g_x[p] == MASK_ID) {
        int s = p & (SS - 1);
        int t = g_x[(s == 0) ? p : p - 1];
        for (int r = 0; r < PW; r++) {
            int old = atomicCAS(&g_tok[r], -1, t);
            if (old == -1 || old == t) break;
        }
    }
    __syncthreads();
    if (p == 0) {
        int n = 0;
        while (n < PW && g_tok[n] >= 0) n++;
        g_pbase = 0; g_pn = n; g_ntok = n;
    }
}

// h partials for current pass: grid (8, KC), block 128
__global__ __launch_bounds__(128) void k_h_part(const float* __restrict__ emb,
                                                const float* __restrict__ W1) {
    __shared__ float se[PW][64];
    __shared__ int s_pn, s_pb;
    int tid = threadIdx.x;
    if (tid == 0) { s_pn = g_pn; s_pb = g_pbase; }
    __syncthreads();
    const int pn = s_pn;
    if (pn == 0) return;
    int col = blockIdx.x * 128 + tid;
    int kc = blockIdx.y, dbase = kc * 64;
    for (int i = tid; i < PW * 64; i += 128) {
        int j = i >> 6, dd = i & 63;
        se[j][dd] = (j < pn) ? emb[(size_t)g_tok[s_pb + j] * DIM + dbase + dd] : 0.f;
    }
    __syncthreads();
    float acc[PW] = {0.f, 0.f, 0.f, 0.f};
    #pragma unroll 4
    for (int dd = 0; dd < 64; dd++) {
        float w = W1[(size_t)(dbase + dd) * DIM + col];
        #pragma unroll
        for (int j = 0; j < PW; j++) acc[j] += se[j][dd] * w;
    }
    #pragma unroll
    for (int j = 0; j < PW; j++) g_hp[kc][j][col] = acc[j];
}

// dual-stream accumulate: 2 independent float4 column streams per thread
template<int NA>
__device__ __forceinline__ void accum2(const float* __restrict__ Wout,
                                       const float (*sh)[64], int dc,
                                       int c0, int c1) {
    float4 a0[NA], a1[NA];
    #pragma unroll
    for (int r = 0; r < NA; r++) {
        a0[r] = make_float4(0.f, 0.f, 0.f, 0.f);
        a1[r] = make_float4(0.f, 0.f, 0.f, 0.f);
    }
    const float* W = Wout + (size_t)dc * 64 * VOCAB;
    #pragma unroll 4
    for (int dd = 0; dd < 64; dd++) {
        float4 w0 = *(const float4*)(W + (size_t)dd * VOCAB + c0);
        float4 w1 = *(const float4*)(W + (size_t)dd * VOCAB + c1);
        #pragma unroll
        for (int r = 0; r < NA; r++) {
            float s = sh[r][dd];
            a0[r].x += s * w0.x; a0[r].y += s * w0.y;
            a0[r].z += s * w0.z; a0[r].w += s * w0.w;
            a1[r].x += s * w1.x; a1[r].y += s * w1.y;
            a1[r].z += s * w1.z; a1[r].w += s * w1.w;
        }
    }
    #pragma unroll
    for (int r = 0; r < NA; r++) {
        *(float4*)&g_lpart[dc][r][c0] = a0[r];
        *(float4*)&g_lpart[dc][r][c1] = a1[r];
    }
}

// single-stream accumulate (edge block)
template<int NA>
__device__ __forceinline__ void accum1(const float* __restrict__ Wout,
                                       const float (*sh)[64], int dc, int c) {
    float4 acc[NA];
    #pragma unroll
    for (int r = 0; r < NA; r++) acc[r] = make_float4(0.f, 0.f, 0.f, 0.f);
    const float* W = Wout + (size_t)dc * 64 * VOCAB + c;
    #pragma unroll 4
    for (int dd = 0; dd < 64; dd++) {
        float4 w = *(const float4*)(W + (size_t)dd * VOCAB);
        #pragma unroll
        for (int r = 0; r < NA; r++) {
            float s = sh[r][dd];
            acc[r].x += s * w.x; acc[r].y += s * w.y;
            acc[r].z += s * w.z; acc[r].w += s * w.w;
        }
    }
    #pragma unroll
    for (int r = 0; r < NA; r++)
        *(float4*)&g_lpart[dc][r][c] = acc[r];
}

// logits partials with fused h-combine+tanh: grid (32, NDCL), block 128
// each thread: 8 cols as two independent float4 streams (2x memory ILP)
__global__ __launch_bounds__(128) void k_logits(const float* __restrict__ Wout) {
    __shared__ float sh[PW][64];
    __shared__ int s_pn;
    int tid = threadIdx.x, dc = blockIdx.y;
    if (tid == 0) s_pn = g_pn;
    __syncthreads();
    const int pn = s_pn;
    if (pn == 0) return;
    for (int i = tid; i < PW * 64; i += 128) {
        int j = i >> 6, dd = i & 63;
        float s = 0.f;
        if (j < pn) {
            int col = dc * 64 + dd;
            #pragma unroll
            for (int kc = 0; kc < KC; kc++) s += g_hp[kc][j][col];
            s = tanhf(s);
        }
        sh[j][dd] = s;
    }
    __syncthreads();
    int c0 = blockIdx.x * 1024 + tid * 4;
    int c1 = c0 + 512;
    if (c1 < VOCAB) {
        switch (pn) {
            case 1: accum2<1>(Wout, sh, dc, c0, c1); break;
            case 2: accum2<2>(Wout, sh, dc, c0, c1); break;
            case 3: accum2<3>(Wout, sh, dc, c0, c1); break;
            default: accum2<PW>(Wout, sh, dc, c0, c1); break;
        }
    } else if (c0 < VOCAB) {
        switch (pn) {
            case 1: accum1<1>(Wout, sh, dc, c0); break;
            case 2: accum1<2>(Wout, sh, dc, c0); break;
            case 3: accum1<3>(Wout, sh, dc, c0); break;
            default: accum1<PW>(Wout, sh, dc, c0); break;
        }
    }
}

// combine + penalty + per-64-chunk wave stats: grid (125, PW), block 256
__global__ __launch_bounds__(256) void k_comb_stats() {
    int j = blockIdx.y;
    if (j >= g_pn) return;
    int slot = g_pbase + j;
    int wv = threadIdx.x >> 6, lane = threadIdx.x & 63;
    int chunk = blockIdx.x * 4 + wv;             // < 500
    int c = chunk * 64 + lane;
    float v = 0.f;
    #pragma unroll
    for (int dc = 0; dc < NDCL; dc++) v += g_lpart[dc][j][c];
    if (c == EXPAND_ID) v -= 1e9f;
    g_rows[slot][c] = v;
    float bv = v; int bi = c;
    #pragma unroll
    for (int off = 1; off < 64; off <<= 1) {
        float ov = __shfl_xor(bv, off, 64);
        int   oi = __shfl_xor(bi, off, 64);
        if (ov > bv || (ov == bv && oi < bi)) { bv = ov; bi = oi; }
    }
    float z = expf(v - bv);
    #pragma unroll
    for (int off = 1; off < 64; off <<= 1)
        z += __shfl_xor(z, off, 64);
    if (lane == 0) {
        g_cmax[slot][chunk]  = bv;
        g_camax[slot][chunk] = bi;
        g_cz[slot][chunk]    = z;
    }
}

// tiny: per new row, full argmax (first-index) -> next-pass tokens (dedup)
__global__ __launch_bounds__(512) void k_next() {
    __shared__ float rf[512];
    __shared__ int   ri[512];
    __shared__ int s_pn, s_pb;
    int tid = threadIdx.x;
    if (tid == 0) { s_pn = g_pn; s_pb = g_pbase; }
    __syncthreads();
    const int pn = s_pn, base = s_pb;
    for (int j = 0; j < pn; j++) {
        int slot = base + j;
        float bv = NEGF; int bi = 0x7fffffff;
        if (tid < NCH) { bv = g_cmax[slot][tid]; bi = g_camax[slot][tid]; }
        rf[tid] = bv; ri[tid] = bi;
        __syncthreads();
        for (int o = 256; o; o >>= 1) {
            if (tid < o) {
                if (rf[tid + o] > rf[tid] ||
                    (rf[tid + o] == rf[tid] && ri[tid + o] < ri[tid])) {
                    rf[tid] = rf[tid + o]; ri[tid] = ri[tid + o];
                }
            }
            __syncthreads();
        }
        if (tid == 0) g_rowx0[slot] = ri[0];
        __syncthreads();
    }
    if (tid == 0) {
        int nt = g_ntok;
        int nb = nt;
        for (int j = 0; j < pn; j++) {
            int t = g_rowx0[base + j];
            bool found = false;
            for (int k = 0; k < nt; k++) if (g_tok[k] == t) { found = true; break; }
            if (!found && nt < ROWS) g_tok[nt++] = t;
        }
        g_pbase = nb; g_pn = nt - nb; g_ntok = nt;
    }
}

// per-row conf, fully parallel across rows: grid ROWS, block 1024
__global__ __launch_bounds__(1024) void k_conf() {
    int slot = blockIdx.x;
    if (slot >= g_pbase) return;        // only rows with computed data
    __shared__ float rf[1024];
    __shared__ float cmv[512];
    __shared__ float cand[CAP];
    __shared__ float sorted_[TOPK];
    __shared__ int s_n;
    __shared__ float s_mx, s_Z;
    __shared__ unsigned s_thr;
    int tid = threadIdx.x;
    // row max
    rf[tid] = (tid < NCH) ? g_cmax[slot][tid] : NEGF;
    __syncthreads();
    for (int o = 512; o; o >>= 1) {
        if (tid < o) rf[tid] = fmaxf(rf[tid], rf[tid + o]);
        __syncthreads();
    }
    if (tid == 0) s_mx = rf[0];
    __syncthreads();
    float mx = s_mx;
    // Z
    rf[tid] = (tid < NCH) ? g_cz[slot][tid] * expf(g_cmax[slot][tid] - mx) : 0.f;
    __syncthreads();
    for (int o = 512; o; o >>= 1) {
        if (tid < o) rf[tid] += rf[tid + o];
        __syncthreads();
    }
    if (tid == 0) { s_Z = rf[0]; s_n = 0; }
    __syncthreads();
    // threshold: 50th-largest chunk max (rank-select over 500)
    if (tid < 512) cmv[tid] = (tid < NCH) ? g_cmax[slot][tid] : NEGF;
    __syncthreads();
    if (tid < NCH) {
        unsigned kt = keyf(cmv[tid]);
        int rank = 0;
        for (int j = 0; j < NCH; j++) {
            unsigned kj = keyf(cmv[j]);
            rank += (kj > kt) || (kj == kt && j < tid);
        }
        if (rank == THRRANK) s_thr = kt;
    }
    __syncthreads();
    unsigned T = s_thr;
    // gather candidates >= T
    const float4* L4 = (const float4*)g_rows[slot];
    for (int i = tid; i < VOCAB / 4; i += 1024) {
        float4 v4 = L4[i];
        float vv[4] = {v4.x, v4.y, v4.z, v4.w};
        #pragma unroll
        for (int q = 0; q < 4; q++) {
            if (keyf(vv[q]) >= T) {
                int j = atomicAdd(&s_n, 1);
                if (j < CAP) cand[j] = vv[q];
            }
        }
    }
    __syncthreads();
    int n = s_n; if (n > CAP) n = CAP;
    // rank-sort top-50 (distinct keys -> order-independent)
    for (int i = tid; i < n; i += 1024) {
        unsigned ki = keyf(cand[i]);
        int rank = 0;
        for (int j = 0; j < n; j++) {
            unsigned kj = keyf(cand[j]);
            rank += (kj > ki) || (kj == ki && j < i);
        }
        if (rank < TOPK) sorted_[rank] = cand[i];
    }
    __syncthreads();
    if (tid == 0) {
        int m = n; if (m > TOPK) m = TOPK;
        float run = expf(sorted_[0] - mx);       // == 1
        float lim = 0.9f * s_Z;
        for (int j = 1; j < m; j++) {
            if (run > lim) break;                // top-p removal boundary
            run += expf(sorted_[j] - mx);
        }
        g_rowconf[slot] = 1.0f / run;
    }
}

// 1 block, 1024 threads: replay all 4 selection steps in LDS + write output
__global__ __launch_bounds__(1024) void k_select(float* __restrict__ out) {
    __shared__ int   xl[BS];
    __shared__ float rf[1024];
    __shared__ int   ri[1024];
    __shared__ int   px0[BS];
    __shared__ int   rtok[ROWS];
    __shared__ float rcf[ROWS];
    __shared__ int   rx0[ROWS];
    __shared__ float stepc[NSTEPS];
    __shared__ int s_nt;
    int p = threadIdx.x;
    xl[p] = g_x[p];
    if (p < ROWS) { rtok[p] = g_tok[p]; rcf[p] = g_rowconf[p]; rx0[p] = g_rowx0[p]; }
    if (p == 0) s_nt = g_pbase;              // computed rows only
    __syncthreads();
    const int nt = s_nt;
    for (int step = 0; step < NSTEPS; step++) {
        float mc = NEGF; int mx0 = 0;
        if (xl[p] == MASK_ID) {
            int s = p & (SS - 1);
            int t = xl[(s == 0) ? p : p - 1];
            for (int k = 0; k < nt; k++) {
                if (rtok[k] == t) { mc = rcf[k]; mx0 = rx0[k]; break; }
            }
        }
        px0[p] = mx0;
        rf[p] = mc; ri[p] = p;
        __syncthreads();
        for (int o = 512; o; o >>= 1) {
            if (p < o) {
                if (rf[p + o] > rf[p] ||
                    (rf[p + o] == rf[p] && ri[p + o] < ri[p])) {
                    rf[p] = rf[p + o]; ri[p] = ri[p + o];
                }
            }
            __syncthreads();
        }
        if (p == 0) {
            stepc[step] = rf[0];
            if (rf[0] > 0.f) xl[ri[0]] = px0[ri[0]];   // any-mask guard
        }
        __syncthreads();
    }
    out[p] = (float)xl[p];
    if (p < NSTEPS) out[BS + p] = stepc[p];
}

extern "C" void kernel_launch(void* const* d_in, const int* in_sizes, int n_in,
                              void* d_out, int out_size, void* d_ws, size_t ws_size,
                              hipStream_t stream) {
    const int*   x    = (const int*)  d_in[0];
    const float* emb  = (const float*)d_in[1];
    const float* W1   = (const float*)d_in[2];
    const float* Wout = (const float*)d_in[3];
    float*       out  = (float*)d_out;

    k_start<<<1, 1024, 0, stream>>>(x);
    for (int pass = 0; pass < NSTEPS; pass++) {
        k_h_part<<<dim3(8, KC), 128, 0, stream>>>(emb, W1);
        k_logits<<<dim3(32, NDCL), 128, 0, stream>>>(Wout);
        k_comb_stats<<<dim3(125, PW), 256, 0, stream>>>();
        k_next<<<1, 512, 0, stream>>>();
    }
    k_conf<<<ROWS, 1024, 0, stream>>>();
    k_select<<<1, 1024, 0, stream>>>(out);
}